// Round 2
// baseline (74.174 us; speedup 1.0000x reference)
//
#include <hip/hip_runtime.h>
#include <math.h>

#define NF 32
#define HH 1024
#define WW 1024

// ---------------------------------------------------------------------------
// Kernel A: compute the 1024 tile colors (output is piecewise-constant on
// 32x32 tiles since all splits land on multiples of 1024/2^5 = 32).
// Per tile: color = sum over 36 root-to-leaf paths (branching k={3,3,2,2,1})
// of prod(path softmax probs) * sigmoid(fc[leaf]).
// Grid: 32 blocks x 256 threads; block b computes tiles [32b, 32b+32).
// Each of the 4 waves handles 8 tiles (36 paths across lanes + shuffle reduce).
// ---------------------------------------------------------------------------

__device__ __forceinline__ int descend(int idx, int py, int px,
                                       int& y0, int& x0, int& h, int& w) {
  int side;
  if (idx & 1) {            // vertical split: columns, side 0 = left
    int lw = w >> 1;
    if (px >= x0 + lw) { side = 1; x0 += lw; w -= lw; }
    else               { side = 0; w = lw; }
  } else {                  // horizontal split: rows, side 0 = top
    int th = h >> 1;
    if (py >= y0 + th) { side = 1; y0 += th; h -= th; }
    else               { side = 0; h = th; }
  }
  return side;
}

__global__ __launch_bounds__(256)
void tiles_kernel(const float* __restrict__ fc,
                  const float* __restrict__ fsel,
                  const int* __restrict__ temp,
                  float4* __restrict__ tileCol) {
  __shared__ float sProbs[64][33];   // [idx*2+side][i], +1 pad
  __shared__ int   sOrder[64][3];    // top-3 indices per (idx, side)
  __shared__ float sSig[NF][3];      // sigmoid(frame_colors)

  const int tid = threadIdx.x;

  // temperature: python int scalar -> int32 array; hedge against float bits
  int   ti = temp[0];
  float t  = (ti > 0 && ti < 1000000) ? (float)ti : __int_as_float(ti);
  const float invT = 1.0f / t;

  // coalesced load of frame_selection (32x2x32 f32), scaled by 1/T
  for (int v = 0; v < 8; ++v) {
    int u = v * 256 + tid;
    sProbs[u >> 5][u & 31] = fsel[u] * invT;
  }
  if (tid >= 64 && tid < 160) {      // sigmoid of frame colors
    int j = tid - 64;
    sSig[j / 3][j % 3] = 1.0f / (1.0f + expf(-fc[j]));
  }
  __syncthreads();

  // one lane per (idx,side) row: softmax + stable top-3
  if (tid < 64) {
    float m = -1e30f;
    for (int i = 0; i < 32; ++i) m = fmaxf(m, sProbs[tid][i]);
    float s = 0.f;
    for (int i = 0; i < 32; ++i) {
      float e = expf(sProbs[tid][i] - m);
      sProbs[tid][i] = e;
      s += e;
    }
    float inv = 1.0f / s;
    float v0 = -1.f, v1 = -1.f, v2 = -1.f;
    int   b0 = 0,    b1 = 0,    b2 = 0;
    for (int i = 0; i < 32; ++i) {
      float p = sProbs[tid][i] * inv;
      sProbs[tid][i] = p;
      // strict > scanning ascending i == np stable argsort(-p) tie behavior
      if (p > v0)      { v2=v1;b2=b1; v1=v0;b1=b0; v0=p;b0=i; }
      else if (p > v1) { v2=v1;b2=b1; v1=p;b1=i; }
      else if (p > v2) { v2=p;b2=i; }
    }
    sOrder[tid][0] = b0; sOrder[tid][1] = b1; sOrder[tid][2] = b2;
  }
  __syncthreads();

  // all 4 waves: 8 tiles each, 36 paths across lanes
  const int wave = tid >> 6;
  const int lane = tid & 63;
  for (int k = 0; k < 8; ++k) {
    const int tile = blockIdx.x * 32 + wave * 8 + k;
    const int py = ((tile >> 5) << 5) + 16;
    const int px = ((tile & 31) << 5) + 16;

    float c0 = 0.f, c1 = 0.f, c2 = 0.f;
    if (lane < 36) {
      int j = lane;
      int sel0 = j / 12; int r = j % 12;
      int sel1 = r / 4;  r &= 3;
      int sel2 = r >> 1;
      int sel3 = r & 1;
      int selArr[5] = { sel0, sel1, sel2, sel3, 0 };

      int idx = 0, ay = 0, ax = 0, ah = HH, aw = WW;
      float w = 1.0f;
      bool alive = true;
      for (int d = 0; d < 5; ++d) {
        int s   = descend(idx, py, px, ay, ax, ah, aw);
        int row = idx * 2 + s;
        int ci  = sOrder[row][selArr[d]];
        float p = sProbs[row][ci];
        if (p <= 1e-3f) { alive = false; break; }  // reference skip rule
        w  *= p;
        idx = ci;
      }
      if (alive) {
        c0 = w * sSig[idx][0];
        c1 = w * sSig[idx][1];
        c2 = w * sSig[idx][2];
      }
    }
    for (int off = 32; off > 0; off >>= 1) {
      c0 += __shfl_down(c0, off, 64);
      c1 += __shfl_down(c1, off, 64);
      c2 += __shfl_down(c2, off, 64);
    }
    if (lane == 0) tileCol[tile] = make_float4(c0, c1, c2, 0.f);
  }
}

// ---------------------------------------------------------------------------
// Kernel B: pure broadcast-write. out is (3, 1024, 1024) f32.
// 1024 blocks x 256 threads; thread g owns pixel-float4 g (262144 total per
// channel plane) and writes it for all 3 channels. Fully coalesced float4.
// ---------------------------------------------------------------------------
__global__ __launch_bounds__(256)
void write_kernel(const float4* __restrict__ tileCol,
                  float4* __restrict__ out4) {
  const int g  = blockIdx.x * 256 + threadIdx.x;  // pixel float4 id
  const int y  = g >> 8;                           // 256 float4 per row
  const int xq = g & 255;
  const int tile = ((y >> 5) << 5) + (xq >> 3);    // 8 float4 per 32-wide tile
  const float4 col = tileCol[tile];                // L2-hot, 128B-coalesced

  out4[g]                   = make_float4(col.x, col.x, col.x, col.x);
  out4[g + (HH * WW / 4)]   = make_float4(col.y, col.y, col.y, col.y);
  out4[g + (HH * WW / 2)]   = make_float4(col.z, col.z, col.z, col.z);
}

extern "C" void kernel_launch(void* const* d_in, const int* in_sizes, int n_in,
                              void* d_out, int out_size, void* d_ws, size_t ws_size,
                              hipStream_t stream) {
  const float* fc   = (const float*)d_in[0];   // (32, 3) f32
  const float* fsel = (const float*)d_in[1];   // (32, 2, 32) f32
  const int*   temp = (const int*)d_in[2];     // scalar
  float4* tileCol = (float4*)d_ws;             // 1024 x float4 = 16 KB
  (void)in_sizes; (void)n_in; (void)out_size; (void)ws_size;

  tiles_kernel<<<dim3(32),   dim3(256), 0, stream>>>(fc, fsel, temp, tileCol);
  write_kernel<<<dim3(1024), dim3(256), 0, stream>>>(tileCol, (float4*)d_out);
}

// Round 3
// 64.968 us; speedup vs baseline: 1.1417x; 1.1417x over previous
//
#include <hip/hip_runtime.h>
#include <math.h>

#define NF 32
#define HH 1024
#define WW 1024

// Output is piecewise-constant on 32x32 tiles (all splits land on multiples
// of 1024/2^5 = 32). Per tile: color = sum over 36 root-to-leaf paths
// (branching k={3,3,2,2,1}) of prod(path softmax probs) * sigmoid(fc[leaf]).
// Single fused kernel, one block per tile (launch count is what matters here:
// the harness's 256MiB d_ws poison dominates the timed region at ~42us).

__device__ __forceinline__ int descend(int idx, int py, int px,
                                       int& y0, int& x0, int& h, int& w) {
  int side;
  if (idx & 1) {            // vertical split: columns, side 0 = left
    int lw = w >> 1;
    if (px >= x0 + lw) { side = 1; x0 += lw; w -= lw; }
    else               { side = 0; w = lw; }
  } else {                  // horizontal split: rows, side 0 = top
    int th = h >> 1;
    if (py >= y0 + th) { side = 1; y0 += th; h -= th; }
    else               { side = 0; h = th; }
  }
  return side;
}

// element-ordering rule matching np stable argsort(-p): p desc, index asc
__device__ __forceinline__ bool better(float pa, int ia, float pb, int ib) {
  return (pa > pb) || (pa == pb && ia < ib);
}

__global__ __launch_bounds__(256)
void fractal_kernel(const float* __restrict__ fc,
                    const float* __restrict__ fsel,
                    const int* __restrict__ temp,
                    float* __restrict__ out) {
  __shared__ float sProbs[64][33];   // [idx*2+side][i], +1 pad: conflict-free
  __shared__ int   sOrder[64][3];    // top-3 indices per (idx, side)
  __shared__ float sSig[NF][3];      // sigmoid(frame_colors)
  __shared__ float sCol[3];          // final tile color

  const int tid  = threadIdx.x;
  const int tile = blockIdx.x;
  const int by = tile >> 5, bx = tile & 31;
  const int py = by * 32 + 16, px = bx * 32 + 16;  // tile interior point

  // temperature: python int scalar -> int32 array; hedge against float bits
  int   ti = temp[0];
  float t  = (ti > 0 && ti < 1000000) ? (float)ti : __int_as_float(ti);
  const float invT = 1.0f / t;

  // phase 1a: coalesced load of frame_selection (32x2x32 f32), scaled by 1/T
  for (int v = 0; v < 8; ++v) {
    int u = v * 256 + tid;
    sProbs[u >> 5][u & 31] = fsel[u] * invT;
  }
  __syncthreads();

  // phase 1b: softmax + stable top-3, 4 lanes per row x 8 entries each.
  // Quad lanes (tid&3) are consecutive -> same wave; __shfl_xor 1,2 reduces.
  {
    const int row = tid >> 2;
    const int sub = tid & 3;
    float* rp = &sProbs[row][sub * 8];

    float m = rp[0];
    #pragma unroll
    for (int i = 1; i < 8; ++i) m = fmaxf(m, rp[i]);
    m = fmaxf(m, __shfl_xor(m, 1, 64));
    m = fmaxf(m, __shfl_xor(m, 2, 64));

    float s = 0.f;
    float e[8];
    #pragma unroll
    for (int i = 0; i < 8; ++i) { e[i] = expf(rp[i] - m); s += e[i]; }
    s += __shfl_xor(s, 1, 64);
    s += __shfl_xor(s, 2, 64);
    const float inv = 1.0f / s;

    float v0 = -1.f, v1 = -1.f, v2 = -1.f;
    int   b0 = 0,    b1 = 0,    b2 = 0;
    #pragma unroll
    for (int i = 0; i < 8; ++i) {
      float p = e[i] * inv;
      rp[i] = p;                       // normalized prob back to LDS
      int gi = sub * 8 + i;
      if (better(p, gi, v0, b0))      { v2=v1;b2=b1; v1=v0;b1=b0; v0=p;b0=gi; }
      else if (better(p, gi, v1, b1)) { v2=v1;b2=b1; v1=p;b1=gi; }
      else if (better(p, gi, v2, b2)) { v2=p;b2=gi; }
    }
    // merge top-3 lists across the quad (xor 1, then xor 2)
    #pragma unroll
    for (int mseq = 1; mseq <= 2; mseq <<= 1) {
      float w0 = __shfl_xor(v0, mseq, 64), w1 = __shfl_xor(v1, mseq, 64),
            w2 = __shfl_xor(v2, mseq, 64);
      int   c0 = __shfl_xor(b0, mseq, 64), c1 = __shfl_xor(b1, mseq, 64),
            c2 = __shfl_xor(b2, mseq, 64);
      float wv[3] = { w0, w1, w2 };
      int   wc[3] = { c0, c1, c2 };
      #pragma unroll
      for (int j = 0; j < 3; ++j) {
        float p = wv[j]; int gi = wc[j];
        if (better(p, gi, v0, b0))      { v2=v1;b2=b1; v1=v0;b1=b0; v0=p;b0=gi; }
        else if (better(p, gi, v1, b1)) { v2=v1;b2=b1; v1=p;b1=gi; }
        else if (better(p, gi, v2, b2)) { v2=p;b2=gi; }
      }
    }
    if (sub == 0) { sOrder[row][0] = b0; sOrder[row][1] = b1; sOrder[row][2] = b2; }
  }
  // sigmoid of frame colors: 96 values on threads 0..95 (overlaps phase 1b
  // rows 0..23 work done above; separate pass keeps it simple)
  if (tid < 96) {
    sSig[tid / 3][tid % 3] = 1.0f / (1.0f + expf(-fc[tid]));
  }
  __syncthreads();

  // phase 2: wave 0 evaluates the 36 root-to-leaf paths (lane j = path j)
  if (tid < 64) {
    const int lane = tid;
    float c0 = 0.f, c1 = 0.f, c2 = 0.f;
    if (lane < 36) {
      int j = lane;
      int sel0 = j / 12; int r = j % 12;
      int sel1 = r / 4;  r &= 3;
      int sel2 = r >> 1;
      int sel3 = r & 1;
      int selArr[5] = { sel0, sel1, sel2, sel3, 0 };

      int idx = 0, ay = 0, ax = 0, ah = HH, aw = WW;
      float w = 1.0f;
      bool alive = true;
      for (int d = 0; d < 5; ++d) {
        int s   = descend(idx, py, px, ay, ax, ah, aw);
        int row = idx * 2 + s;
        int ci  = sOrder[row][selArr[d]];
        float p = sProbs[row][ci];
        if (p <= 1e-3f) { alive = false; break; }  // reference skip rule
        w  *= p;
        idx = ci;
      }
      if (alive) {
        c0 = w * sSig[idx][0];
        c1 = w * sSig[idx][1];
        c2 = w * sSig[idx][2];
      }
    }
    for (int off = 32; off > 0; off >>= 1) {
      c0 += __shfl_down(c0, off, 64);
      c1 += __shfl_down(c1, off, 64);
      c2 += __shfl_down(c2, off, 64);
    }
    if (tid == 0) { sCol[0] = c0; sCol[1] = c1; sCol[2] = c2; }
  }
  __syncthreads();

  // phase 3: broadcast-write the tile. out layout (3, 1024, 1024) C-order.
  // 256 threads x 3 channels x 1 float4 = 3072 floats = 32x32x3. Coalesced.
  const int r = tid >> 3;   // row in tile
  const int q = tid & 7;    // float4 slot in row
  for (int c = 0; c < 3; ++c) {
    float v = sCol[c];
    float4 val = make_float4(v, v, v, v);
    float* base = out + (size_t)c * (HH * WW)
                      + (size_t)(by * 32 + r) * WW + (size_t)bx * 32;
    ((float4*)base)[q] = val;
  }
}

extern "C" void kernel_launch(void* const* d_in, const int* in_sizes, int n_in,
                              void* d_out, int out_size, void* d_ws, size_t ws_size,
                              hipStream_t stream) {
  const float* fc   = (const float*)d_in[0];   // (32, 3) f32
  const float* fsel = (const float*)d_in[1];   // (32, 2, 32) f32
  const int*   temp = (const int*)d_in[2];     // scalar
  float* out = (float*)d_out;                  // (3, 1024, 1024) f32
  (void)in_sizes; (void)n_in; (void)out_size; (void)d_ws; (void)ws_size;
  fractal_kernel<<<dim3(1024), dim3(256), 0, stream>>>(fc, fsel, temp, out);
}

// Round 5
// 64.765 us; speedup vs baseline: 1.1453x; 1.0031x over previous
//
#include <hip/hip_runtime.h>
#include <math.h>

#define NF 32
#define HH 1024
#define WW 1024

// native vector type for __builtin_nontemporal_store (HIP float4 is a class)
typedef float nfloat4 __attribute__((ext_vector_type(4)));

// Output is piecewise-constant on 32x32 tiles (all split boundaries land on
// multiples of 1024/2^5 = 32). Per tile: color = sum over 36 root-to-leaf
// paths (branching k={3,3,2,2,1}) of prod(path softmax probs)*sigmoid(fc[leaf]).
// Single dispatch (round 2 showed a 2nd dispatch costs ~8us in this harness);
// one block per tile; the 256MiB d_ws re-poison (~41us) dominates the timing.

__device__ __forceinline__ int descend(int idx, int py, int px,
                                       int& y0, int& x0, int& h, int& w) {
  int side;
  if (idx & 1) {            // vertical split: columns, side 0 = left
    int lw = w >> 1;
    if (px >= x0 + lw) { side = 1; x0 += lw; w -= lw; }
    else               { side = 0; w = lw; }
  } else {                  // horizontal split: rows, side 0 = top
    int th = h >> 1;
    if (py >= y0 + th) { side = 1; y0 += th; h -= th; }
    else               { side = 0; h = th; }
  }
  return side;
}

// ordering matching np stable argsort(-p): value desc, index asc.
// Applied to RAW logits (exp is monotone -> same order as probs; raw-logit
// compare reproduces the f64-prob tie semantics better than f32 probs).
__device__ __forceinline__ bool better(float pa, int ia, float pb, int ib) {
  return (pa > pb) || (pa == pb && ia < ib);
}

__global__ __launch_bounds__(256)
void fractal_kernel(const float* __restrict__ fc,
                    const float* __restrict__ fsel,
                    const int* __restrict__ temp,
                    float* __restrict__ out) {
  __shared__ float sLogit[64][33];   // [idx*2+side][i] scaled logits, +1 pad
  __shared__ float sTop[64][4];      // top-3 normalized probs per row
  __shared__ int   sOrder[64][4];    // top-3 indices per row
  __shared__ float sSig[NF][3];      // sigmoid(frame_colors)

  const int tid  = threadIdx.x;
  const int tile = blockIdx.x;
  const int by = tile >> 5, bx = tile & 31;
  const int py = by * 32 + 16, px = bx * 32 + 16;  // tile interior point

  // temperature: python int scalar -> int32 array; hedge against float bits
  int   ti = temp[0];
  float t  = (ti > 0 && ti < 1000000) ? (float)ti : __int_as_float(ti);
  const float invT = 1.0f / t;

  // phase 1a: coalesced load of frame_selection (32x2x32 f32), scaled by 1/T
  for (int v = 0; v < 8; ++v) {
    int u = v * 256 + tid;
    sLogit[u >> 5][u & 31] = fsel[u] * invT;
  }
  if (tid < 96) {                      // sigmoid of frame colors (32x3)
    sSig[tid / 3][tid % 3] = 1.0f / (1.0f + expf(-fc[tid]));
  }
  __syncthreads();

  // phase 1b: per-row softmax sum + top-3, 4 lanes per row x 8 entries.
  // Quad lanes (tid&3) are consecutive -> same wave; __shfl_xor 1,2 reduce.
  {
    const int row = tid >> 2;
    const int sub = tid & 3;
    const float* rp = &sLogit[row][sub * 8];

    float raw[8];
    #pragma unroll
    for (int i = 0; i < 8; ++i) raw[i] = rp[i];

    float m = raw[0];
    #pragma unroll
    for (int i = 1; i < 8; ++i) m = fmaxf(m, raw[i]);
    m = fmaxf(m, __shfl_xor(m, 1, 64));
    m = fmaxf(m, __shfl_xor(m, 2, 64));

    float s = 0.f;
    #pragma unroll
    for (int i = 0; i < 8; ++i) s += expf(raw[i] - m);
    s += __shfl_xor(s, 1, 64);
    s += __shfl_xor(s, 2, 64);

    // stable top-3 on raw logits (no exp needed for selection)
    float v0 = -1e30f, v1 = -1e30f, v2 = -1e30f;
    int   b0 = 0,      b1 = 0,      b2 = 0;
    #pragma unroll
    for (int i = 0; i < 8; ++i) {
      float p = raw[i]; int gi = sub * 8 + i;
      if (better(p, gi, v0, b0))      { v2=v1;b2=b1; v1=v0;b1=b0; v0=p;b0=gi; }
      else if (better(p, gi, v1, b1)) { v2=v1;b2=b1; v1=p;b1=gi; }
      else if (better(p, gi, v2, b2)) { v2=p;b2=gi; }
    }
    #pragma unroll
    for (int mseq = 1; mseq <= 2; mseq <<= 1) {
      float w0 = __shfl_xor(v0, mseq, 64), w1 = __shfl_xor(v1, mseq, 64),
            w2 = __shfl_xor(v2, mseq, 64);
      int   c0 = __shfl_xor(b0, mseq, 64), c1 = __shfl_xor(b1, mseq, 64),
            c2 = __shfl_xor(b2, mseq, 64);
      float wv[3] = { w0, w1, w2 };
      int   wc[3] = { c0, c1, c2 };
      #pragma unroll
      for (int j = 0; j < 3; ++j) {
        float p = wv[j]; int gi = wc[j];
        if (better(p, gi, v0, b0))      { v2=v1;b2=b1; v1=v0;b1=b0; v0=p;b0=gi; }
        else if (better(p, gi, v1, b1)) { v2=v1;b2=b1; v1=p;b1=gi; }
        else if (better(p, gi, v2, b2)) { v2=p;b2=gi; }
      }
    }
    if (sub == 0) {
      const float inv = 1.0f / s;
      sTop[row][0] = expf(v0 - m) * inv;
      sTop[row][1] = expf(v1 - m) * inv;
      sTop[row][2] = expf(v2 - m) * inv;
      sOrder[row][0] = b0; sOrder[row][1] = b1; sOrder[row][2] = b2;
    }
  }
  __syncthreads();

  // phase 2: every wave evaluates the 36 paths (lanes 36..63 contribute 0);
  // full xor-butterfly leaves the tile color in ALL lanes -> no extra sync.
  const int wave = tid >> 6;
  const int lane = tid & 63;
  float c0 = 0.f, c1 = 0.f, c2 = 0.f;
  if (lane < 36) {
    int j = lane;
    int sel0 = j / 12; int r = j % 12;
    int sel1 = r / 4;  r &= 3;
    int sel2 = r >> 1;
    int sel3 = r & 1;
    int selArr[5] = { sel0, sel1, sel2, sel3, 0 };

    int idx = 0, ay = 0, ax = 0, ah = HH, aw = WW;
    float w = 1.0f;
    bool alive = true;
    for (int d = 0; d < 5; ++d) {
      int s   = descend(idx, py, px, ay, ax, ah, aw);
      int row = idx * 2 + s;
      int ci  = sOrder[row][selArr[d]];
      float p = sTop[row][selArr[d]];
      if (p <= 1e-3f) { alive = false; break; }  // reference skip rule
      w  *= p;
      idx = ci;
    }
    if (alive) {
      c0 = w * sSig[idx][0];
      c1 = w * sSig[idx][1];
      c2 = w * sSig[idx][2];
    }
  }
  #pragma unroll
  for (int off = 32; off > 0; off >>= 1) {
    c0 += __shfl_xor(c0, off, 64);
    c1 += __shfl_xor(c1, off, 64);
    c2 += __shfl_xor(c2, off, 64);
  }

  // phase 3: each wave streams out its 8 rows of the tile immediately.
  // out layout (3, 1024, 1024); 32-float rows = 8 float4, 128B-aligned.
  // Non-temporal: zero reuse, keep L2 for the other blocks' fsel reads.
  const int r = wave * 8 + (lane >> 3);   // row in tile
  const int q = lane & 7;                 // float4 slot in row
  float* base0 = out + (size_t)(by * 32 + r) * WW + (size_t)bx * 32;
  nfloat4 p0 = { c0, c0, c0, c0 };
  nfloat4 p1 = { c1, c1, c1, c1 };
  nfloat4 p2 = { c2, c2, c2, c2 };
  __builtin_nontemporal_store(p0, (nfloat4*)base0 + q);
  __builtin_nontemporal_store(p1, (nfloat4*)(base0 + HH * WW) + q);
  __builtin_nontemporal_store(p2, (nfloat4*)(base0 + 2 * HH * WW) + q);
}

extern "C" void kernel_launch(void* const* d_in, const int* in_sizes, int n_in,
                              void* d_out, int out_size, void* d_ws, size_t ws_size,
                              hipStream_t stream) {
  const float* fc   = (const float*)d_in[0];   // (32, 3) f32
  const float* fsel = (const float*)d_in[1];   // (32, 2, 32) f32
  const int*   temp = (const int*)d_in[2];     // scalar
  float* out = (float*)d_out;                  // (3, 1024, 1024) f32
  (void)in_sizes; (void)n_in; (void)out_size; (void)d_ws; (void)ws_size;
  fractal_kernel<<<dim3(1024), dim3(256), 0, stream>>>(fc, fsel, temp, out);
}